// Round 1
// baseline (130.169 us; speedup 1.0000x reference)
//
#include <hip/hip_runtime.h>

// ChunkedEmbedding == plain gather: out[row, :] = weight[indices[row], :]
//   indices: int32 [4096*200]  (d_in[0])
//   weight:  f32   [100000,128] (d_in[1])
//   out:     f32   [4096*200,128]
//
// Memory-bound. 128 f32 per row = 32 float4. One float4 per lane,
// 32 consecutive lanes share a row (idx read is a broadcast). Grid-stride.

__global__ __launch_bounds__(256) void ChunkedEmbedding_27255862460962_kernel(
    const int* __restrict__ idx,
    const float* __restrict__ weight,
    float* __restrict__ out,
    long nrows) {
    const long total = nrows * 32;  // float4 elements total
    const long stride = (long)gridDim.x * blockDim.x;
    for (long i = (long)blockIdx.x * blockDim.x + threadIdx.x; i < total; i += stride) {
        const long row = i >> 5;          // which output row
        const int  c   = (int)(i & 31);   // which float4 within the row
        const long e   = (long)idx[row];  // wave-uniform per 32-lane group
        const float4 v = reinterpret_cast<const float4*>(weight + e * 128)[c];
        reinterpret_cast<float4*>(out + row * 128)[c] = v;
    }
}

extern "C" void kernel_launch(void* const* d_in, const int* in_sizes, int n_in,
                              void* d_out, int out_size, void* d_ws, size_t ws_size,
                              hipStream_t stream) {
    const int*   idx    = (const int*)d_in[0];
    const float* weight = (const float*)d_in[1];
    float*       out    = (float*)d_out;

    const long nrows = (long)in_sizes[0];      // 4096*200 = 819200
    const long total = nrows * 32;             // float4 work items

    const int block = 256;
    long grid = (total + block - 1) / block;
    if (grid > 2048) grid = 2048;              // grid-stride the rest

    ChunkedEmbedding_27255862460962_kernel<<<(int)grid, block, 0, stream>>>(
        idx, weight, out, nrows);
}

// Round 3
// 123.999 us; speedup vs baseline: 1.0498x; 1.0498x over previous
//
#include <hip/hip_runtime.h>

// ChunkedEmbedding == plain gather: out[row, :] = weight[indices[row], :]
//   indices: int32 [4096*200]  (d_in[0])
//   weight:  f32   [100000,128] (d_in[1])
//   out:     f32   [4096*200,128]
//
// Memory-bound. 128 f32 per row = 32 float4; one float4/lane, 32 consecutive
// lanes share a row (idx load is a broadcast). Grid-stride.
//
// Key: the 419 MB output stream has zero reuse — store it NONTEMPORAL so it
// doesn't evict the 51 MB weight table from L2/L3. Round 1 showed read
// traffic ~= write traffic (no L3 absorption) purely from write pollution.
//
// Note: __builtin_nontemporal_store requires a clang ext_vector_type, not
// HIP's float4 struct.

typedef float f32x4 __attribute__((ext_vector_type(4)));

__global__ __launch_bounds__(256) void ChunkedEmbedding_27255862460962_kernel(
    const int* __restrict__ idx,
    const float* __restrict__ weight,
    float* __restrict__ out,
    long nrows) {
    const long total = nrows * 32;  // float4 elements total
    const long stride = (long)gridDim.x * blockDim.x;
    for (long i = (long)blockIdx.x * blockDim.x + threadIdx.x; i < total; i += stride) {
        const long row = i >> 5;          // which output row
        const int  c   = (int)(i & 31);   // which float4 within the row
        const long e   = (long)idx[row];  // wave-uniform per 32-lane group
        const f32x4 v = reinterpret_cast<const f32x4*>(weight + e * 128)[c];
        __builtin_nontemporal_store(v, reinterpret_cast<f32x4*>(out + row * 128) + c);
    }
}

extern "C" void kernel_launch(void* const* d_in, const int* in_sizes, int n_in,
                              void* d_out, int out_size, void* d_ws, size_t ws_size,
                              hipStream_t stream) {
    const int*   idx    = (const int*)d_in[0];
    const float* weight = (const float*)d_in[1];
    float*       out    = (float*)d_out;

    const long nrows = (long)in_sizes[0];      // 4096*200 = 819200
    const long total = nrows * 32;             // float4 work items

    const int block = 256;
    long grid = (total + block - 1) / block;
    if (grid > 2048) grid = 2048;              // grid-stride the rest

    ChunkedEmbedding_27255862460962_kernel<<<(int)grid, block, 0, stream>>>(
        idx, weight, out, nrows);
}